// Round 1
// baseline (495.232 us; speedup 1.0000x reference)
//
#include <hip/hip_runtime.h>
#include <math.h>

#define EPS 1e-9f

// ---------------------------------------------------------------------------
// Kernel A: scale = 1 / (||psi|| + eps)
// ---------------------------------------------------------------------------
__global__ __launch_bounds__(256) void psi_norm_kernel(const float* __restrict__ psi,
                                                       int D,
                                                       float* __restrict__ scale_out) {
    __shared__ float red[8];
    const int tid = threadIdx.x;
    float s = 0.f;
    for (int i = tid; i < D; i += blockDim.x) {
        float v = psi[i];
        s += v * v;
    }
    // 64-lane wave reduce
    for (int off = 32; off > 0; off >>= 1) s += __shfl_xor(s, off);
    const int lane = tid & 63, wave = tid >> 6;
    if (lane == 0) red[wave] = s;
    __syncthreads();
    if (tid == 0) {
        const int nwaves = blockDim.x >> 6;
        float t = 0.f;
        for (int w = 0; w < nwaves; ++w) t += red[w];
        scale_out[0] = 1.0f / (sqrtf(t) + EPS);
    }
}

// ---------------------------------------------------------------------------
// Kernel B: sims[row] = dot(row, psi) * scale / (||row|| + eps)
// One wave (64 lanes) per row; float4 coalesced loads; single pass fuses
// dot-product and row-norm accumulation. psi staged in LDS per block.
// Assumes D % 256 == 0 and D <= 1024 (here D = 1024).
// ---------------------------------------------------------------------------
__global__ __launch_bounds__(256) void sim_kernel(const float4* __restrict__ vocab,
                                                  const float4* __restrict__ psi4,
                                                  const float* __restrict__ scale_ptr,
                                                  float* __restrict__ sims,
                                                  int V, int D) {
    __shared__ float4 psi_lds[256];  // up to D = 1024 floats
    const int tid = threadIdx.x;
    const int D4 = D >> 2;           // 256 for D=1024
    for (int i = tid; i < D4; i += blockDim.x) psi_lds[i] = psi4[i];
    __syncthreads();

    const int lane = tid & 63;
    const int wave = tid >> 6;
    const int wavesPerBlock = blockDim.x >> 6;
    const int gwave = blockIdx.x * wavesPerBlock + wave;
    const int nwaves = gridDim.x * wavesPerBlock;
    const float scale = scale_ptr[0];
    const int iters = D4 >> 6;       // float4-chunks per lane (4 for D=1024)

    for (int row = gwave; row < V; row += nwaves) {
        const float4* rp = vocab + (size_t)row * D4;
        float dot = 0.f, nrm = 0.f;
#pragma unroll 4
        for (int it = 0; it < iters; ++it) {
            float4 a = rp[it * 64 + lane];
            float4 p = psi_lds[it * 64 + lane];
            dot += a.x * p.x + a.y * p.y + a.z * p.z + a.w * p.w;
            nrm += a.x * a.x + a.y * a.y + a.z * a.z + a.w * a.w;
        }
        for (int off = 32; off > 0; off >>= 1) {
            dot += __shfl_xor(dot, off);
            nrm += __shfl_xor(nrm, off);
        }
        if (lane == 0) sims[row] = dot * scale / (sqrtf(nrm) + EPS);
    }
}

// ---------------------------------------------------------------------------
// Kernel C: top-K over sims (single block). Iterative argmax with exclusion;
// tie-break prefers the lowest index (matches jax.lax.top_k).
// out[0..K-1] = scores, out[K..2K-1] = indices (as float).
// ---------------------------------------------------------------------------
__global__ __launch_bounds__(1024) void topk_kernel(const float* __restrict__ sims,
                                                    int V, int K,
                                                    float* __restrict__ out) {
    __shared__ float sval[16];
    __shared__ int   sidx[16];
    __shared__ int   bidx_sh;
    const int tid = threadIdx.x;
    const int lane = tid & 63, wave = tid >> 6;
    const int nthreads = blockDim.x;
    const int nwaves = nthreads >> 6;

    int sel[8];
#pragma unroll
    for (int i = 0; i < 8; ++i) sel[i] = -1;

    for (int k = 0; k < K; ++k) {
        float lv = -INFINITY;
        int   li = -1;
        for (int i = tid; i < V; i += nthreads) {
            float v = sims[i];
            bool excl = false;
            for (int j = 0; j < k; ++j) excl |= (sel[j] == i);
            if (!excl && v > lv) { lv = v; li = i; }  // strict > keeps lowest idx per thread
        }
        // 64-lane wave reduce of (val, idx); higher val wins, tie -> lower idx
        for (int off = 32; off > 0; off >>= 1) {
            float ov = __shfl_xor(lv, off);
            int   oi = __shfl_xor(li, off);
            if ((oi >= 0) && (ov > lv || (ov == lv && (li < 0 || oi < li)))) { lv = ov; li = oi; }
        }
        if (lane == 0) { sval[wave] = lv; sidx[wave] = li; }
        __syncthreads();
        if (tid == 0) {
            float bv = sval[0];
            int   bi = sidx[0];
            for (int w = 1; w < nwaves; ++w) {
                float ov = sval[w]; int oi = sidx[w];
                if ((oi >= 0) && (ov > bv || (ov == bv && (bi < 0 || oi < bi)))) { bv = ov; bi = oi; }
            }
            bidx_sh = bi;
            out[k]     = bv;
            out[K + k] = (float)bi;
        }
        __syncthreads();
        sel[k] = bidx_sh;
        // next iteration's sval/sidx writes are ordered after this read by the
        // __syncthreads() that follows them, so no extra barrier needed here
    }
}

extern "C" void kernel_launch(void* const* d_in, const int* in_sizes, int n_in,
                              void* d_out, int out_size, void* d_ws, size_t ws_size,
                              hipStream_t stream) {
    const float* psi   = (const float*)d_in[0];
    const float* vocab = (const float*)d_in[1];
    const int D = in_sizes[0];           // 1024
    const int V = in_sizes[1] / D;       // 128000
    const int K = out_size / 2;          // 5

    float* ws    = (float*)d_ws;
    float* scale = ws;                   // 1 float
    float* sims  = ws + 256;             // V floats (aligned region)

    psi_norm_kernel<<<1, 256, 0, stream>>>(psi, D, scale);

    const int blocks = 2048;             // grid-stride, ~8 blocks/CU scheduling room
    sim_kernel<<<blocks, 256, 0, stream>>>((const float4*)vocab, (const float4*)psi,
                                           scale, sims, V, D);

    topk_kernel<<<1, 1024, 0, stream>>>(sims, V, K, (float*)d_out);
}

// Round 2
// 130.060 us; speedup vs baseline: 3.8077x; 3.8077x over previous
//
#include <hip/hip_runtime.h>
#include <math.h>
#include <limits.h>

#define EPS  1e-9f
#define TOPK 5

// strict total order: higher val wins; on equal val, lower index wins
__device__ __forceinline__ bool better(float av, int ai, float bv, int bi) {
    return (av > bv) || (av == bv && ai < bi);
}

// insert (v,idx) into desc-sorted top-TOPK register arrays.
// Fully unrolled, all indices compile-time after unroll (no scratch).
__device__ __forceinline__ void insert_top(float sv[TOPK], int si[TOPK], float v, int idx) {
    if (!better(v, idx, sv[TOPK - 1], si[TOPK - 1])) return;
    sv[TOPK - 1] = v; si[TOPK - 1] = idx;
#pragma unroll
    for (int j = TOPK - 1; j > 0; --j) {
        if (better(sv[j], si[j], sv[j - 1], si[j - 1])) {
            float tv = sv[j]; sv[j] = sv[j - 1]; sv[j - 1] = tv;
            int   ti = si[j]; si[j] = si[j - 1]; si[j - 1] = ti;
        }
    }
}

// ---------------------------------------------------------------------------
// Kernel A: scale = 1 / (||psi|| + eps)
// ---------------------------------------------------------------------------
__global__ __launch_bounds__(256) void psi_norm_kernel(const float* __restrict__ psi,
                                                       int D,
                                                       float* __restrict__ scale_out) {
    __shared__ float red[8];
    const int tid = threadIdx.x;
    float s = 0.f;
    for (int i = tid; i < D; i += blockDim.x) {
        float v = psi[i];
        s += v * v;
    }
    for (int off = 32; off > 0; off >>= 1) s += __shfl_xor(s, off);
    const int lane = tid & 63, wave = tid >> 6;
    if (lane == 0) red[wave] = s;
    __syncthreads();
    if (tid == 0) {
        const int nwaves = blockDim.x >> 6;
        float t = 0.f;
        for (int w = 0; w < nwaves; ++w) t += red[w];
        scale_out[0] = 1.0f / (sqrtf(t) + EPS);
    }
}

// ---------------------------------------------------------------------------
// Kernel B (fused): per-row cosine sim + per-block top-5 candidates.
// One wave per row (grid-stride); float4 coalesced loads; dot + row-norm in
// one pass; lane 0 keeps a running top-5; waves merge via LDS; block writes
// 5 (val, idx) candidates. sims are never materialized.
// Assumes D % 256 == 0 (D = 1024 here).
// ---------------------------------------------------------------------------
__global__ __launch_bounds__(256) void sim_top_kernel(const float4* __restrict__ vocab,
                                                      const float4* __restrict__ psi4,
                                                      const float* __restrict__ scale_ptr,
                                                      float* __restrict__ cand_v,
                                                      int* __restrict__ cand_i,
                                                      int V, int D) {
    __shared__ float4 psi_lds[256];           // up to D = 1024 floats
    __shared__ float  wv[4 * TOPK];
    __shared__ int    wi[4 * TOPK];
    const int tid = threadIdx.x;
    const int D4  = D >> 2;
    for (int i = tid; i < D4; i += blockDim.x) psi_lds[i] = psi4[i];
    __syncthreads();

    const int lane = tid & 63;
    const int wave = tid >> 6;
    const int wavesPerBlock = blockDim.x >> 6;
    const int gwave  = blockIdx.x * wavesPerBlock + wave;
    const int nwaves = gridDim.x * wavesPerBlock;
    const float scale = scale_ptr[0];
    const int iters = D4 >> 6;                // float4 chunks per lane (4 for D=1024)

    float tv[TOPK]; int ti[TOPK];
#pragma unroll
    for (int j = 0; j < TOPK; ++j) { tv[j] = -INFINITY; ti[j] = INT_MAX; }

    for (int row = gwave; row < V; row += nwaves) {
        const float4* rp = vocab + (size_t)row * D4;
        float dot = 0.f, nrm = 0.f;
#pragma unroll 4
        for (int it = 0; it < iters; ++it) {
            float4 a = rp[it * 64 + lane];
            float4 p = psi_lds[it * 64 + lane];
            dot += a.x * p.x + a.y * p.y + a.z * p.z + a.w * p.w;
            nrm += a.x * a.x + a.y * a.y + a.z * a.z + a.w * a.w;
        }
        for (int off = 32; off > 0; off >>= 1) {
            dot += __shfl_xor(dot, off);
            nrm += __shfl_xor(nrm, off);
        }
        if (lane == 0) {
            float sim = dot * scale / (sqrtf(nrm) + EPS);
            insert_top(tv, ti, sim, row);
        }
    }

    if (lane == 0) {
#pragma unroll
        for (int j = 0; j < TOPK; ++j) { wv[wave * TOPK + j] = tv[j]; wi[wave * TOPK + j] = ti[j]; }
    }
    __syncthreads();
    if (tid == 0) {
        float bv[TOPK]; int bi[TOPK];
#pragma unroll
        for (int j = 0; j < TOPK; ++j) { bv[j] = -INFINITY; bi[j] = INT_MAX; }
        for (int e = 0; e < wavesPerBlock * TOPK; ++e) insert_top(bv, bi, wv[e], wi[e]);
#pragma unroll
        for (int j = 0; j < TOPK; ++j) {
            cand_v[blockIdx.x * TOPK + j] = bv[j];
            cand_i[blockIdx.x * TOPK + j] = bi[j];
        }
    }
}

// ---------------------------------------------------------------------------
// Kernel C: reduce NC candidates -> global top-K. Single block.
// Per-thread register top-5 -> wave butterfly merge (shfl_xor) -> LDS ->
// thread-0 final merge. out[0..K-1] = scores, out[K..2K-1] = indices (float).
// ---------------------------------------------------------------------------
__global__ __launch_bounds__(1024) void topk_reduce_kernel(const float* __restrict__ cand_v,
                                                           const int* __restrict__ cand_i,
                                                           int NC, int K,
                                                           float* __restrict__ out) {
    __shared__ float wv[16 * TOPK];
    __shared__ int   wi[16 * TOPK];
    const int tid = threadIdx.x;
    const int lane = tid & 63, wave = tid >> 6;
    const int nwaves = blockDim.x >> 6;

    float sv[TOPK]; int si[TOPK];
#pragma unroll
    for (int j = 0; j < TOPK; ++j) { sv[j] = -INFINITY; si[j] = INT_MAX; }

    for (int i = tid; i < NC; i += blockDim.x) insert_top(sv, si, cand_v[i], cand_i[i]);

    // 64-lane butterfly merge of sorted-5 lists
    for (int step = 1; step < 64; step <<= 1) {
        float ov[TOPK]; int oi[TOPK];
#pragma unroll
        for (int j = 0; j < TOPK; ++j) {
            ov[j] = __shfl_xor(sv[j], step);
            oi[j] = __shfl_xor(si[j], step);
        }
#pragma unroll
        for (int j = 0; j < TOPK; ++j) insert_top(sv, si, ov[j], oi[j]);
    }

    if (lane == 0) {
#pragma unroll
        for (int j = 0; j < TOPK; ++j) { wv[wave * TOPK + j] = sv[j]; wi[wave * TOPK + j] = si[j]; }
    }
    __syncthreads();
    if (tid == 0) {
        float bv[TOPK]; int bi[TOPK];
#pragma unroll
        for (int j = 0; j < TOPK; ++j) { bv[j] = -INFINITY; bi[j] = INT_MAX; }
        for (int e = 0; e < nwaves * TOPK; ++e) insert_top(bv, bi, wv[e], wi[e]);
        for (int k = 0; k < K && k < TOPK; ++k) {
            out[k]     = bv[k];
            out[K + k] = (float)bi[k];
        }
    }
}

extern "C" void kernel_launch(void* const* d_in, const int* in_sizes, int n_in,
                              void* d_out, int out_size, void* d_ws, size_t ws_size,
                              hipStream_t stream) {
    const float* psi   = (const float*)d_in[0];
    const float* vocab = (const float*)d_in[1];
    const int D = in_sizes[0];           // 1024
    const int V = in_sizes[1] / D;       // 128000
    const int K = out_size / 2;          // 5

    const int blocks = 2048;             // 8 blocks/CU, full occupancy
    const int NC = blocks * TOPK;        // 10240 candidates

    float* ws     = (float*)d_ws;
    float* scale  = ws;                                  // 1 float
    float* cand_v = ws + 256;                            // NC floats
    int*   cand_i = (int*)(ws + 256 + NC);               // NC ints

    psi_norm_kernel<<<1, 256, 0, stream>>>(psi, D, scale);

    sim_top_kernel<<<blocks, 256, 0, stream>>>((const float4*)vocab, (const float4*)psi,
                                               scale, cand_v, cand_i, V, D);

    topk_reduce_kernel<<<1, 1024, 0, stream>>>(cand_v, cand_i, NC, K, (float*)d_out);
}

// Round 3
// 113.747 us; speedup vs baseline: 4.3538x; 1.1434x over previous
//
#include <hip/hip_runtime.h>
#include <math.h>
#include <limits.h>

#define EPS  1e-9f
#define TOPK 5

typedef float v4f __attribute__((ext_vector_type(4)));

// strict total order: higher val wins; on equal val, lower index wins
__device__ __forceinline__ bool better(float av, int ai, float bv, int bi) {
    return (av > bv) || (av == bv && ai < bi);
}

// insert (v,idx) into desc-sorted top-TOPK register arrays.
// Fully unrolled, all indices compile-time after unroll (no scratch).
__device__ __forceinline__ void insert_top(float sv[TOPK], int si[TOPK], float v, int idx) {
    if (!better(v, idx, sv[TOPK - 1], si[TOPK - 1])) return;
    sv[TOPK - 1] = v; si[TOPK - 1] = idx;
#pragma unroll
    for (int j = TOPK - 1; j > 0; --j) {
        if (better(sv[j], si[j], sv[j - 1], si[j - 1])) {
            float tv = sv[j]; sv[j] = sv[j - 1]; sv[j - 1] = tv;
            int   ti = si[j]; si[j] = si[j - 1]; si[j - 1] = ti;
        }
    }
}

__device__ __forceinline__ float dot4(v4f a, v4f b) {
    return a.x * b.x + a.y * b.y + a.z * b.z + a.w * b.w;
}

// ---------------------------------------------------------------------------
// Fused kernel: psi-norm (wave-redundant, from register fragments) +
// per-row cosine sim + per-block top-5 candidates.
// One wave per row-PAIR (contiguous 8 KB stream, 8 independent float4 loads
// in flight); psi held in 16 VGPRs (lane's chunks identical for every row —
// no LDS in the hot loop). Assumes D == 1024 (row = 256 float4 chunks).
// ---------------------------------------------------------------------------
__global__ __launch_bounds__(256) void sim_top_kernel(const v4f* __restrict__ vocab,
                                                      const v4f* __restrict__ psi4,
                                                      float* __restrict__ cand_v,
                                                      int* __restrict__ cand_i,
                                                      int V) {
    __shared__ float wvs[4 * TOPK];
    __shared__ int   wis[4 * TOPK];
    const int tid  = threadIdx.x;
    const int lane = tid & 63;
    const int wave = tid >> 6;
    const int wavesPerBlock = blockDim.x >> 6;
    const int gwave  = blockIdx.x * wavesPerBlock + wave;
    const int nwaves = gridDim.x * wavesPerBlock;

    // psi fragments in registers: 64 lanes x 4 chunks = all 256 float4 of psi.
    const v4f p0 = psi4[lane];
    const v4f p1 = psi4[64 + lane];
    const v4f p2 = psi4[128 + lane];
    const v4f p3 = psi4[192 + lane];

    // wave-redundant ||psi||^2 -> scale (identical add order in every wave ->
    // bitwise-identical scale across the grid, deterministic)
    float ps = dot4(p0, p0) + dot4(p1, p1) + dot4(p2, p2) + dot4(p3, p3);
    for (int off = 32; off > 0; off >>= 1) ps += __shfl_xor(ps, off);
    const float scale = 1.0f / (sqrtf(ps) + EPS);

    float tv[TOPK]; int ti[TOPK];
#pragma unroll
    for (int j = 0; j < TOPK; ++j) { tv[j] = -INFINITY; ti[j] = INT_MAX; }

    const int NP = V >> 1;  // contiguous row pairs
    for (int p = gwave; p < NP; p += nwaves) {
        const v4f* ra = vocab + (size_t)(2 * p) * 256;
        const v4f* rb = ra + 256;
        v4f a0 = __builtin_nontemporal_load(ra + lane);
        v4f a1 = __builtin_nontemporal_load(ra + 64 + lane);
        v4f a2 = __builtin_nontemporal_load(ra + 128 + lane);
        v4f a3 = __builtin_nontemporal_load(ra + 192 + lane);
        v4f b0 = __builtin_nontemporal_load(rb + lane);
        v4f b1 = __builtin_nontemporal_load(rb + 64 + lane);
        v4f b2 = __builtin_nontemporal_load(rb + 128 + lane);
        v4f b3 = __builtin_nontemporal_load(rb + 192 + lane);

        float dotA = dot4(a0, p0) + dot4(a1, p1) + dot4(a2, p2) + dot4(a3, p3);
        float nrmA = dot4(a0, a0) + dot4(a1, a1) + dot4(a2, a2) + dot4(a3, a3);
        float dotB = dot4(b0, p0) + dot4(b1, p1) + dot4(b2, p2) + dot4(b3, p3);
        float nrmB = dot4(b0, b0) + dot4(b1, b1) + dot4(b2, b2) + dot4(b3, b3);

        // four independent butterfly chains, interleaved
        for (int off = 32; off > 0; off >>= 1) {
            dotA += __shfl_xor(dotA, off);
            nrmA += __shfl_xor(nrmA, off);
            dotB += __shfl_xor(dotB, off);
            nrmB += __shfl_xor(nrmB, off);
        }
        if (lane == 0) {
            insert_top(tv, ti, dotA * scale / (sqrtf(nrmA) + EPS), 2 * p);
            insert_top(tv, ti, dotB * scale / (sqrtf(nrmB) + EPS), 2 * p + 1);
        }
    }

    // odd-V tail (not hit for V=128000): one wave handles the last row
    if ((V & 1) && gwave == 0) {
        const int row = V - 1;
        const v4f* ra = vocab + (size_t)row * 256;
        v4f a0 = ra[lane], a1 = ra[64 + lane], a2 = ra[128 + lane], a3 = ra[192 + lane];
        float dotA = dot4(a0, p0) + dot4(a1, p1) + dot4(a2, p2) + dot4(a3, p3);
        float nrmA = dot4(a0, a0) + dot4(a1, a1) + dot4(a2, a2) + dot4(a3, a3);
        for (int off = 32; off > 0; off >>= 1) {
            dotA += __shfl_xor(dotA, off);
            nrmA += __shfl_xor(nrmA, off);
        }
        if (lane == 0) insert_top(tv, ti, dotA * scale / (sqrtf(nrmA) + EPS), row);
    }

    if (lane == 0) {
#pragma unroll
        for (int j = 0; j < TOPK; ++j) { wvs[wave * TOPK + j] = tv[j]; wis[wave * TOPK + j] = ti[j]; }
    }
    __syncthreads();
    if (tid == 0) {
        float bv[TOPK]; int bi[TOPK];
#pragma unroll
        for (int j = 0; j < TOPK; ++j) { bv[j] = -INFINITY; bi[j] = INT_MAX; }
        for (int e = 0; e < wavesPerBlock * TOPK; ++e) insert_top(bv, bi, wvs[e], wis[e]);
#pragma unroll
        for (int j = 0; j < TOPK; ++j) {
            cand_v[blockIdx.x * TOPK + j] = bv[j];
            cand_i[blockIdx.x * TOPK + j] = bi[j];
        }
    }
}

// ---------------------------------------------------------------------------
// Reduce NC candidates -> global top-K. Single block; per-thread register
// top-5 -> wave butterfly merge -> LDS -> thread-0 final merge.
// out[0..K-1] = scores, out[K..2K-1] = indices (as float).
// ---------------------------------------------------------------------------
__global__ __launch_bounds__(1024) void topk_reduce_kernel(const float* __restrict__ cand_v,
                                                           const int* __restrict__ cand_i,
                                                           int NC, int K,
                                                           float* __restrict__ out) {
    __shared__ float wvs[16 * TOPK];
    __shared__ int   wis[16 * TOPK];
    const int tid = threadIdx.x;
    const int lane = tid & 63, wave = tid >> 6;
    const int nwaves = blockDim.x >> 6;

    float sv[TOPK]; int si[TOPK];
#pragma unroll
    for (int j = 0; j < TOPK; ++j) { sv[j] = -INFINITY; si[j] = INT_MAX; }

    for (int i = tid; i < NC; i += blockDim.x) insert_top(sv, si, cand_v[i], cand_i[i]);

    for (int step = 1; step < 64; step <<= 1) {
        float ov[TOPK]; int oi[TOPK];
#pragma unroll
        for (int j = 0; j < TOPK; ++j) {
            ov[j] = __shfl_xor(sv[j], step);
            oi[j] = __shfl_xor(si[j], step);
        }
#pragma unroll
        for (int j = 0; j < TOPK; ++j) insert_top(sv, si, ov[j], oi[j]);
    }

    if (lane == 0) {
#pragma unroll
        for (int j = 0; j < TOPK; ++j) { wvs[wave * TOPK + j] = sv[j]; wis[wave * TOPK + j] = si[j]; }
    }
    __syncthreads();
    if (tid == 0) {
        float bv[TOPK]; int bi[TOPK];
#pragma unroll
        for (int j = 0; j < TOPK; ++j) { bv[j] = -INFINITY; bi[j] = INT_MAX; }
        for (int e = 0; e < nwaves * TOPK; ++e) insert_top(bv, bi, wvs[e], wis[e]);
        for (int k = 0; k < K && k < TOPK; ++k) {
            out[k]     = bv[k];
            out[K + k] = (float)bi[k];
        }
    }
}

extern "C" void kernel_launch(void* const* d_in, const int* in_sizes, int n_in,
                              void* d_out, int out_size, void* d_ws, size_t ws_size,
                              hipStream_t stream) {
    const float* psi   = (const float*)d_in[0];
    const float* vocab = (const float*)d_in[1];
    const int D = in_sizes[0];           // 1024 (kernel assumes this)
    const int V = in_sizes[1] / D;       // 128000
    const int K = out_size / 2;          // 5
    (void)D;

    // 2000 blocks -> 8000 waves; 64000 row-pairs / 8000 = exactly 8 pairs/wave
    const int blocks = 2000;
    const int NC = blocks * TOPK;        // 10000 candidates

    float* cand_v = (float*)d_ws;
    int*   cand_i = (int*)((float*)d_ws + NC);

    sim_top_kernel<<<blocks, 256, 0, stream>>>((const v4f*)vocab, (const v4f*)psi,
                                               cand_v, cand_i, V);

    topk_reduce_kernel<<<1, 1024, 0, stream>>>(cand_v, cand_i, NC, K, (float*)d_out);
}